// Round 17
// baseline (920.612 us; speedup 1.0000x reference)
//
#include <hip/hip_runtime.h>
#include <hip/hip_bf16.h>

// Problem dims (fixed by setup_inputs)
constexpr int kNS = 16384;   // support rows
constexpr int kNQ = 8192;    // query rows
constexpr int kD  = 256;     // feature dim
constexpr int kC  = 64;      // classes

// R16 PASSED (753 us; main MFMA 157 us; rest = ~600 us long tail).
// R17: (1) k_logits -> GEMM tile + fused log-softmax (was per-query shuffle
// chains); (2) proto segment-sum via 64KB-LDS accumulation (was 4.2M global
// atomics); (3) rowabs+cnorm fused. Row norms precomputed once (k_norms).

// ---------------- workspace layout (float offsets into d_ws), ~24.4 MB ----
constexpr size_t OFF_PSUM  = 0;
constexpr size_t OFF_PCNT  = 16384;
constexpr size_t OFF_MUSUM = 16448;
constexpr size_t OFF_XTX   = 16704;
constexpr size_t OFF_HIST  = 82240;
constexpr size_t OFF_SSUM  = 84288;
constexpr size_t ZERO_FLOATS = 84352;
constexpr size_t OFF_PROTO = 84352;
constexpr size_t OFF_MU    = 100736;
constexpr size_t OFF_COV   = 100992;
constexpr size_t OFF_C     = 166784;    // [0]=c (inf-norm), [1]=gamma
constexpr size_t OFF_Y     = 166800;    // Newton X ping
constexpr size_t OFF_T     = 297872;    // Newton T
constexpr size_t OFF_Y2    = 363408;    // Newton X pong
constexpr size_t OFF_SNINV = 428944;    // 16384 inv norms (support)
constexpr size_t OFF_QNINV = 445328;    // 8192 inv norms (query)
constexpr size_t OFF_S2    = 560016;
constexpr size_t OFF_Q2P   = 576400;
constexpr size_t OFF_PART  = 584592;
constexpr size_t OFF_G     = 846736;    // 8192*256 f32
constexpr size_t OFF_SH    = 2943888;   // 16384*256 bf16 swizzled
constexpr size_t OFF_GH    = 5041040;   // 8192*256 bf16 swizzled

typedef __attribute__((ext_vector_type(8))) short bf16x8;
typedef __attribute__((ext_vector_type(4))) float f32x4;

__device__ __forceinline__ unsigned short f2bf(float f) {
  unsigned int w; __builtin_memcpy(&w, &f, 4);
  unsigned int r = (w + 0x7FFFu + ((w >> 16) & 1u)) >> 16;
  return (unsigned short)r;
}

__device__ __forceinline__ float waveReduceSum(float v) {
#pragma unroll
  for (int off = 32; off > 0; off >>= 1) v += __shfl_xor(v, off);
  return v;
}
__device__ __forceinline__ float waveReduceMax(float v) {
#pragma unroll
  for (int off = 32; off > 0; off >>= 1) v = fmaxf(v, __shfl_xor(v, off));
  return v;
}
__device__ __forceinline__ void fma16(float acc[4][4], float4 a, float4 b) {
  acc[0][0] += a.x*b.x; acc[0][1] += a.x*b.y; acc[0][2] += a.x*b.z; acc[0][3] += a.x*b.w;
  acc[1][0] += a.y*b.x; acc[1][1] += a.y*b.y; acc[1][2] += a.y*b.z; acc[1][3] += a.y*b.w;
  acc[2][0] += a.z*b.x; acc[2][1] += a.z*b.y; acc[2][2] += a.z*b.z; acc[2][3] += a.z*b.w;
  acc[3][0] += a.w*b.x; acc[3][1] += a.w*b.y; acc[3][2] += a.w*b.z; acc[3][3] += a.w*b.w;
}

__global__ void k_zero_r17(float* __restrict__ ws) {
  size_t i = (size_t)blockIdx.x * 256 + threadIdx.x;
  if (i < ZERO_FLOATS) ws[i] = 0.f;
}

// f32 [rows x 256] -> bf16 fragment-major swizzle (one block per 16-row group)
__global__ void k_swz_r17(const float* __restrict__ in, unsigned short* __restrict__ out) {
  int g = blockIdx.x, t = threadIdx.x;
  int ks = t >> 5;
  size_t gbase = (size_t)g * 4096;
#pragma unroll
  for (int f = 0; f < 2; ++f) {
    int lane = (2 * t + f) & 63;
    int q = lane >> 4, r = lane & 15;
    const float* src = &in[(size_t)(g * 16 + r) * kD + ks * 32 + q * 8];
    float4 v0 = *(const float4*)src;
    float4 v1 = *(const float4*)(src + 4);
    ushort4 o0, o1;
    o0.x = f2bf(v0.x); o0.y = f2bf(v0.y); o0.z = f2bf(v0.z); o0.w = f2bf(v0.w);
    o1.x = f2bf(v1.x); o1.y = f2bf(v1.y); o1.z = f2bf(v1.z); o1.w = f2bf(v1.w);
    unsigned short* dst = &out[gbase + (size_t)ks * 512 + (size_t)lane * 8];
    *(ushort4*)dst = o0;
    *(ushort4*)(dst + 4) = o1;
  }
}

// inverse L2 norms of SF rows (0..16383) and QF rows (16384..24575)
__global__ void k_norms_r17(const float* __restrict__ SF, const float* __restrict__ QF,
                            float* __restrict__ sninv, float* __restrict__ qninv) {
  int w = threadIdx.x >> 6, lane = threadIdx.x & 63;
  int ridx = blockIdx.x * 4 + w;
  const float* src; float* dst; int row;
  if (ridx < kNS) { src = SF; dst = sninv; row = ridx; }
  else            { src = QF; dst = qninv; row = ridx - kNS; }
  float4 v = *(const float4*)&src[(size_t)row * kD + lane * 4];
  float ss = waveReduceSum(v.x*v.x + v.y*v.y + v.z*v.z + v.w*v.w);
  if (lane == 0) dst[row] = 1.0f / fmaxf(sqrtf(ss), 1e-8f);
}

// ---------------- classification path ----------------
// LDS-accumulated segment sum of normalized support rows. 16 blocks x 1024 rows.
__global__ void __launch_bounds__(256) k_proto_lds_r17(
    const float* __restrict__ X, const int* __restrict__ lab,
    const float* __restrict__ sninv, float* __restrict__ psum,
    float* __restrict__ pcnt) {
  __shared__ float ps[kC * kD];     // 64 KB
  int t = threadIdx.x;
  for (int i = t; i < kC * kD; i += 256) ps[i] = 0.f;
  __syncthreads();
  int w = t >> 6, lane = t & 63;
  int base = blockIdx.x * 1024;
  for (int r = w; r < 1024; r += 4) {
    int row = base + r;
    int l = lab[row];
    float inv = sninv[row];
    float4 v = *(const float4*)&X[(size_t)row * kD + lane * 4];
    float* p = &ps[l * kD + lane * 4];
    atomicAdd(p + 0, v.x * inv); atomicAdd(p + 1, v.y * inv);
    atomicAdd(p + 2, v.z * inv); atomicAdd(p + 3, v.w * inv);
    if (lane == 0) atomicAdd(&pcnt[l], 1.0f);   // global, 16384 total
  }
  __syncthreads();
  for (int i = t; i < kC * kD; i += 256) atomicAdd(&psum[i], ps[i]);
}

__global__ void k_proto_fin_r17(const float* __restrict__ psum, const float* __restrict__ pcnt,
                                float* __restrict__ protos) {
  int c = blockIdx.x, lane = threadIdx.x;
  float4 v = *(const float4*)&psum[(size_t)c * kD + lane * 4];
  float cnt = fmaxf(pcnt[c], 1.0f);
  v.x /= cnt; v.y /= cnt; v.z /= cnt; v.w /= cnt;
  float ss = waveReduceSum(v.x*v.x + v.y*v.y + v.z*v.z + v.w*v.w);
  float inv = 1.0f / fmaxf(sqrtf(ss), 1e-8f);
  float4 o = {v.x*inv, v.y*inv, v.z*inv, v.w*inv};
  *(float4*)&protos[(size_t)c * kD + lane * 4] = o;
}

// logits GEMM (64 queries x 64 classes per block) + fused log-softmax
__global__ void k_logits_r17(const float* __restrict__ Q, const float* __restrict__ qninv,
                             const float* __restrict__ protos, float* __restrict__ out0) {
  __shared__ alignas(16) float As[16][68];
  __shared__ alignas(16) float Bs[16][68];
  __shared__ float lg[64][68];
  __shared__ float lses[64];
  int t = threadIdx.x, tx = t & 15, ty = t >> 4;
  int mb = blockIdx.x * 64;
  float acc[4][4] = {};
  for (int k0 = 0; k0 < 256; k0 += 16) {
    __syncthreads();
    {
      int kk = t & 15, m0 = t >> 4;
#pragma unroll
      for (int p = 0; p < 4; ++p) {
        int m = m0 + p * 16;
        As[kk][m] = Q[(size_t)(mb + m) * kD + k0 + kk];
      }
      int j = t & 63, kr0 = t >> 6;
#pragma unroll
      for (int p = 0; p < 4; ++p) {
        int kr = kr0 + p * 4;
        Bs[kr][j] = protos[(size_t)j * kD + k0 + kr];   // transpose-stage
      }
    }
    __syncthreads();
#pragma unroll
    for (int k = 0; k < 16; ++k) {
      float4 a = *(const float4*)&As[k][ty * 4];
      float4 b = *(const float4*)&Bs[k][tx * 4];
      fma16(acc, a, b);
    }
  }
  __syncthreads();
#pragma unroll
  for (int r = 0; r < 4; ++r) {
    int lr = ty * 4 + r;
    float qi = qninv[mb + lr];
#pragma unroll
    for (int c = 0; c < 4; ++c) lg[lr][tx * 4 + c] = acc[r][c] * qi;
  }
  __syncthreads();
  if (t < 64) {
    float m = -1e30f;
#pragma unroll
    for (int c = 0; c < kC; ++c) m = fmaxf(m, lg[t][c]);
    float s = 0.f;
#pragma unroll
    for (int c = 0; c < kC; ++c) s += __expf(lg[t][c] - m);
    lses[t] = m + __logf(s);
  }
  __syncthreads();
#pragma unroll
  for (int i = 0; i < 16; ++i) {
    int idx = i * 256 + t;                 // coalesced
    int row = idx >> 6, col = idx & 63;
    out0[(size_t)(mb + row) * kC + col] = lg[row][col] - lses[row];
  }
}

// ---------------- regression path ----------------
__global__ void k_colsum_r17(const float* __restrict__ X, float* __restrict__ musum) {
  int t = threadIdx.x;
  int r0 = blockIdx.x * 64;
  float s = 0.f;
  for (int r = 0; r < 64; ++r) s += X[(size_t)(r0 + r) * kD + t];
  atomicAdd(&musum[t], s);
}
__global__ void k_mufin_r17(const float* __restrict__ musum, float* __restrict__ mu) {
  int t = threadIdx.x;
  mu[t] = musum[t] * (1.0f / (float)kNS);
}

__global__ void k_xtx_r17(const float* __restrict__ X, float* __restrict__ xtx) {
  __shared__ alignas(16) float As[16][68];
  __shared__ alignas(16) float Bs[16][68];
  int t = threadIdx.x, tx = t & 15, ty = t >> 4;
  int ab = (blockIdx.x >> 2) * 64, bb = (blockIdx.x & 3) * 64;
  int k0b = blockIdx.y * 1024;
  float acc[4][4] = {};
  for (int k0 = 0; k0 < 1024; k0 += 16) {
    __syncthreads();
    int j = t & 63, kr0 = t >> 6;
#pragma unroll
    for (int p = 0; p < 4; ++p) {
      int kr = kr0 + p * 4;
      size_t base = (size_t)(k0b + k0 + kr) * kD;
      As[kr][j] = X[base + ab + j];
      Bs[kr][j] = X[base + bb + j];
    }
    __syncthreads();
#pragma unroll
    for (int k = 0; k < 16; ++k) {
      float4 a = *(const float4*)&As[k][ty * 4];
      float4 b = *(const float4*)&Bs[k][tx * 4];
      fma16(acc, a, b);
    }
  }
#pragma unroll
  for (int r = 0; r < 4; ++r)
#pragma unroll
    for (int c = 0; c < 4; ++c)
      atomicAdd(&xtx[(size_t)(ab + ty * 4 + r) * kD + bb + tx * 4 + c], acc[r][c]);
}

__global__ void k_cov_r17(const float* __restrict__ xtx, const float* __restrict__ mu,
                          float* __restrict__ cov) {
  int i = blockIdx.x, j = threadIdx.x;
  float v = (xtx[(size_t)i * kD + j] - (float)kNS * mu[i] * mu[j]) * (1.0f / (float)(kNS - 1));
  if (i == j) v += 1e-4f;
  cov[(size_t)i * kD + j] = v;
}

// fused inf-norm of cov (single block; thread t owns row t)
__global__ void k_cnorm1_r17(const float* __restrict__ cov, float* __restrict__ cptr) {
  __shared__ float red[4];
  int t = threadIdx.x;
  const float* row = &cov[(size_t)t * kD];
  float s = 0.f;
  for (int j = 0; j < kD; j += 4) {
    float4 v = *(const float4*)&row[j];
    s += fabsf(v.x) + fabsf(v.y) + fabsf(v.z) + fabsf(v.w);
  }
  float m = waveReduceMax(s);
  if ((t & 63) == 0) red[t >> 6] = m;
  __syncthreads();
  if (t == 0) cptr[0] = fmaxf(fmaxf(red[0], red[1]), fmaxf(red[2], red[3]));
}

// X0 = I / c
__global__ void k_newt_init_r17(const float* __restrict__ cptr, float* __restrict__ X) {
  int i = blockIdx.x, j = threadIdx.x;
  X[(size_t)i * kD + j] = (i == j) ? (1.0f / cptr[0]) : 0.0f;
}

// T = 2I - cov @ X
__global__ void k_newt_T_r17(const float* __restrict__ A, const float* __restrict__ X,
                             float* __restrict__ T) {
  int i = blockIdx.x, j = threadIdx.x;
  const float* arow = &A[(size_t)i * kD];
  float s0 = 0.f, s1 = 0.f, s2 = 0.f, s3 = 0.f;
#pragma unroll 4
  for (int k = 0; k < kD; k += 4) {
    s0 = fmaf(arow[k + 0], X[(size_t)(k + 0) * kD + j], s0);
    s1 = fmaf(arow[k + 1], X[(size_t)(k + 1) * kD + j], s1);
    s2 = fmaf(arow[k + 2], X[(size_t)(k + 2) * kD + j], s2);
    s3 = fmaf(arow[k + 3], X[(size_t)(k + 3) * kD + j], s3);
  }
  float s = (s0 + s1) + (s2 + s3);
  T[(size_t)i * kD + j] = (i == j ? 2.0f : 0.0f) - s;
}

// Xn = X @ T
__global__ void k_newt_X_r17(const float* __restrict__ X, const float* __restrict__ T,
                             float* __restrict__ Xn) {
  int i = blockIdx.x, j = threadIdx.x;
  const float* xrow = &X[(size_t)i * kD];
  float s0 = 0.f, s1 = 0.f, s2 = 0.f, s3 = 0.f;
#pragma unroll 4
  for (int k = 0; k < kD; k += 4) {
    s0 = fmaf(xrow[k + 0], T[(size_t)(k + 0) * kD + j], s0);
    s1 = fmaf(xrow[k + 1], T[(size_t)(k + 1) * kD + j], s1);
    s2 = fmaf(xrow[k + 2], T[(size_t)(k + 2) * kD + j], s2);
    s3 = fmaf(xrow[k + 3], T[(size_t)(k + 3) * kD + j], s3);
  }
  Xn[(size_t)i * kD + j] = (s0 + s1) + (s2 + s3);
}

// G = (Q - mu) @ M
__global__ void k_G_r17(const float* __restrict__ Q, const float* __restrict__ mu,
                        const float* __restrict__ M, float* __restrict__ G) {
  __shared__ alignas(16) float As[16][68];
  __shared__ alignas(16) float Bs[16][68];
  int t = threadIdx.x, tx = t & 15, ty = t >> 4;
  int nb = blockIdx.x * 64;
  int mb = blockIdx.y * 64;
  float acc[4][4] = {};
  for (int k0 = 0; k0 < 256; k0 += 16) {
    __syncthreads();
    {
      int kk = t & 15, m0 = t >> 4;
      float muk = mu[k0 + kk];
#pragma unroll
      for (int p = 0; p < 4; ++p) {
        int m = m0 + p * 16;
        As[kk][m] = Q[(size_t)(mb + m) * kD + k0 + kk] - muk;
      }
      int j = t & 63, kr0 = t >> 6;
#pragma unroll
      for (int p = 0; p < 4; ++p) {
        int kr = kr0 + p * 4;
        Bs[kr][j] = M[(size_t)(k0 + kr) * kD + nb + j];
      }
    }
    __syncthreads();
#pragma unroll
    for (int k = 0; k < 16; ++k) {
      float4 a = *(const float4*)&As[k][ty * 4];
      float4 b = *(const float4*)&Bs[k][tx * 4];
      fma16(acc, a, b);
    }
  }
#pragma unroll
  for (int r = 0; r < 4; ++r) {
    int gi = mb + ty * 4 + r;
    float4 o = {acc[r][0], acc[r][1], acc[r][2], acc[r][3]};
    *(float4*)&G[(size_t)gi * kD + nb + tx * 4] = o;
  }
}

// q2p[i] = G_i . (Q_i + mu)
__global__ void k_q2p_r17(const float* __restrict__ G, const float* __restrict__ Q,
                          const float* __restrict__ mu, float* __restrict__ q2p) {
  int w = threadIdx.x >> 6, lane = threadIdx.x & 63;
  int row = blockIdx.x * 4 + w;
  float4 g = *(const float4*)&G[(size_t)row * kD + lane * 4];
  float4 q = *(const float4*)&Q[(size_t)row * kD + lane * 4];
  float4 m = *(const float4*)&mu[lane * 4];
  float ss = waveReduceSum(g.x*(q.x+m.x) + g.y*(q.y+m.y) + g.z*(q.z+m.z) + g.w*(q.w+m.w));
  if (lane == 0) q2p[row] = ss;
}

// s2[j] = (S_j - mu) M (S_j - mu), per 64-row chunk
__global__ void k_s2_r17(const float* __restrict__ S, const float* __restrict__ mu,
                         const float* __restrict__ M, float* __restrict__ s2) {
  __shared__ alignas(16) float As[16][68];
  __shared__ alignas(16) float Bs[16][68];
  __shared__ float red[64][17];
  int t = threadIdx.x, tx = t & 15, ty = t >> 4;
  int mb = blockIdx.x * 64;
  float partial[4] = {0.f, 0.f, 0.f, 0.f};
  for (int ntile = 0; ntile < 4; ++ntile) {
    int nb = ntile * 64;
    float acc[4][4] = {};
    for (int k0 = 0; k0 < 256; k0 += 16) {
      __syncthreads();
      {
        int kk = t & 15, m0 = t >> 4;
        float muk = mu[k0 + kk];
#pragma unroll
        for (int p = 0; p < 4; ++p) {
          int m = m0 + p * 16;
          As[kk][m] = S[(size_t)(mb + m) * kD + k0 + kk] - muk;
        }
        int j = t & 63, kr0 = t >> 6;
#pragma unroll
        for (int p = 0; p < 4; ++p) {
          int kr = kr0 + p * 4;
          Bs[kr][j] = M[(size_t)(k0 + kr) * kD + nb + j];
        }
      }
      __syncthreads();
#pragma unroll
      for (int k = 0; k < 16; ++k) {
        float4 a = *(const float4*)&As[k][ty * 4];
        float4 b = *(const float4*)&Bs[k][tx * 4];
        fma16(acc, a, b);
      }
    }
#pragma unroll
    for (int r = 0; r < 4; ++r) {
      int gi = mb + ty * 4 + r;
#pragma unroll
      for (int c = 0; c < 4; ++c) {
        int gj = nb + tx * 4 + c;
        partial[r] += acc[r][c] * (S[(size_t)gi * kD + gj] - mu[gj]);
      }
    }
  }
  __syncthreads();
#pragma unroll
  for (int r = 0; r < 4; ++r) red[ty * 4 + r][tx] = partial[r];
  __syncthreads();
  if (t < 64) {
    float s = 0.f;
#pragma unroll
    for (int x = 0; x < 16; ++x) s += red[t][x];
    s2[mb + t] = s;
  }
}

// GEMM-tiled sampled-median histogram
__global__ void k_median_r17(const float* __restrict__ G, const float* __restrict__ S,
                             const float* __restrict__ q2p, const float* __restrict__ s2,
                             unsigned int* __restrict__ hist, float* __restrict__ ssum) {
  __shared__ alignas(16) float As[16][68];
  __shared__ alignas(16) float Bs[16][68];
  __shared__ unsigned int h[2048];
  __shared__ float fred[4];
  int t = threadIdx.x, tx = t & 15, ty = t >> 4;
  int stile = blockIdx.x, qtile = blockIdx.y;
  for (int i = t; i < 2048; i += 256) h[i] = 0u;

  float acc[4][4] = {};
  for (int k0 = 0; k0 < 256; k0 += 16) {
    __syncthreads();
    {
      int kk = t & 15, m0 = t >> 4;
#pragma unroll
      for (int p = 0; p < 4; ++p) {
        int m = m0 + p * 16;
        As[kk][m] = G[(size_t)((qtile * 64 + m) * 8) * kD + k0 + kk];
        Bs[kk][m] = S[(size_t)((stile * 64 + m) * 8) * kD + k0 + kk];
      }
    }
    __syncthreads();
#pragma unroll
    for (int k = 0; k < 16; ++k) {
      float4 a = *(const float4*)&As[k][ty * 4];
      float4 b = *(const float4*)&Bs[k][tx * 4];
      fma16(acc, a, b);
    }
  }
  float fsum = 0.f;
#pragma unroll
  for (int r = 0; r < 4; ++r) {
    int qi = (qtile * 64 + ty * 4 + r) * 8;
    float q2v = q2p[qi];
#pragma unroll
    for (int c = 0; c < 4; ++c) {
      int sj = (stile * 64 + tx * 4 + c) * 8;
      float d2 = fmaxf(q2v + s2[sj] - 2.0f * acc[r][c], 0.0f);
      fsum += d2;
      int bin = (int)(d2 * 2.0f);
      bin = bin > 2047 ? 2047 : bin;
      atomicAdd(&h[bin], 1u);
    }
  }
  float wsum = waveReduceSum(fsum);
  if ((t & 63) == 0) fred[t >> 6] = wsum;
  __syncthreads();
  if (t == 0) atomicAdd(ssum, fred[0] + fred[1] + fred[2] + fred[3]);
  for (int i = t; i < 2048; i += 256)
    if (h[i]) atomicAdd(&hist[i], h[i]);
}

// Parallel median + gamma
__global__ void k_gamma_r17(const unsigned int* __restrict__ hist,
                            const float* __restrict__ ssum, float* __restrict__ gptr) {
  __shared__ unsigned int ps[256];
  __shared__ float v0s, v1s;
  int t = threadIdx.x;
  unsigned int mine[8];
  unsigned int c = 0;
#pragma unroll
  for (int j = 0; j < 8; ++j) { mine[j] = hist[t * 8 + j]; c += mine[j]; }
  ps[t] = c;
  __syncthreads();
  for (int off = 1; off < 256; off <<= 1) {
    unsigned int v = (t >= off) ? ps[t - off] : 0u;
    __syncthreads();
    ps[t] += v;
    __syncthreads();
  }
  unsigned int total = ps[255];
  unsigned int before = ps[t] - c;
  if (t == 0) { v0s = 0.f; v1s = 0.f; }
  __syncthreads();
  unsigned int rr0 = (total - 1) / 2, rr1 = total / 2;
  unsigned int cum = before;
#pragma unroll
  for (int j = 0; j < 8; ++j) {
    unsigned int cc = mine[j];
    if (cc > 0) {
      int bin = t * 8 + j;
      if (cum <= rr0 && rr0 < cum + cc) {
        float frac = (float)(rr0 - cum) + 0.5f;
        v0s = ((float)bin + frac / (float)cc) * 0.5f;
      }
      if (cum <= rr1 && rr1 < cum + cc) {
        float frac = (float)(rr1 - cum) + 0.5f;
        v1s = ((float)bin + frac / (float)cc) * 0.5f;
      }
    }
    cum += cc;
  }
  __syncthreads();
  if (t == 0) {
    float med = 0.5f * (v0s + v1s);
    float mean = (total > 0) ? (ssum[0] / (float)total) : 1.0f;
    float g = (med > 0.f) ? 1.0f / (med + 1e-6f) : 1.0f / (mean + 1e-6f);
    gptr[0] = g;
  }
}

// MAIN (MFMA, swizzled operands): grid (128 q-tiles, 16 s-chunks).
__global__ void PrototypicalHead_6210522710389_kernel(
    const unsigned short* __restrict__ Gh, const unsigned short* __restrict__ Sh,
    const float* __restrict__ q2p, const float* __restrict__ s2,
    const float* __restrict__ svals, const float* __restrict__ gptr,
    float* __restrict__ part) {
  int t = threadIdx.x;
  int w = t >> 6, lane = t & 63;
  int l15 = lane & 15, quad = lane >> 4;
  int qt = blockIdx.x, sc = blockIdx.y;
  int qbase = qt * 64;
  float gamma = gptr[0];

  size_t agrp = (size_t)(qt * 4 + w) * 4096;
  bf16x8 afrag[8];
#pragma unroll
  for (int ks = 0; ks < 8; ++ks)
    afrag[ks] = *(const bf16x8*)&Gh[agrp + (size_t)ks * 512 + (size_t)lane * 8];

  float q2v[4];
#pragma unroll
  for (int r = 0; r < 4; ++r) q2v[r] = q2p[qbase + w * 16 + quad * 4 + r];

  float dAcc[4] = {0.f, 0.f, 0.f, 0.f}, nAcc[4] = {0.f, 0.f, 0.f, 0.f};

  for (int st = 0; st < 16; ++st) {
    int sbase = sc * 1024 + st * 64;
    int sgrp = sbase >> 4;
    f32x4 acc0 = {0.f, 0.f, 0.f, 0.f};
    f32x4 acc1 = {0.f, 0.f, 0.f, 0.f};
    f32x4 acc2 = {0.f, 0.f, 0.f, 0.f};
    f32x4 acc3 = {0.f, 0.f, 0.f, 0.f};
    const unsigned short* B0 = &Sh[(size_t)(sgrp + 0) * 4096 + (size_t)lane * 8];
    const unsigned short* B1 = &Sh[(size_t)(sgrp + 1) * 4096 + (size_t)lane * 8];
    const unsigned short* B2 = &Sh[(size_t)(sgrp + 2) * 4096 + (size_t)lane * 8];
    const unsigned short* B3 = &Sh[(size_t)(sgrp + 3) * 4096 + (size_t)lane * 8];
#pragma unroll
    for (int ks = 0; ks < 8; ++ks) {
      bf16x8 f0 = *(const bf16x8*)(B0 + ks * 512);
      bf16x8 f1 = *(const bf16x8*)(B1 + ks * 512);
      bf16x8 f2 = *(const bf16x8*)(B2 + ks * 512);
      bf16x8 f3 = *(const bf16x8*)(B3 + ks * 512);
      acc0 = __builtin_amdgcn_mfma_f32_16x16x32_bf16(afrag[ks], f0, acc0, 0, 0, 0);
      acc1 = __builtin_amdgcn_mfma_f32_16x16x32_bf16(afrag[ks], f1, acc1, 0, 0, 0);
      acc2 = __builtin_amdgcn_mfma_f32_16x16x32_bf16(afrag[ks], f2, acc2, 0, 0, 0);
      acc3 = __builtin_amdgcn_mfma_f32_16x16x32_bf16(afrag[ks], f3, acc3, 0, 0, 0);
    }
#pragma unroll
    for (int nt = 0; nt < 4; ++nt) {
      f32x4 a = (nt == 0) ? acc0 : (nt == 1) ? acc1 : (nt == 2) ? acc2 : acc3;
      int scol = sbase + nt * 16 + l15;
      float s2v = s2[scol];
      float sv = svals[scol];
#pragma unroll
      for (int r = 0; r < 4; ++r) {
        float d2 = fmaxf(q2v[r] + s2v - 2.0f * a[r], 0.0f);
        float e = __expf(-gamma * d2);
        dAcc[r] += e;
        nAcc[r] += e * sv;
      }
    }
  }
#pragma unroll
  for (int off = 8; off >= 1; off >>= 1) {
#pragma unroll
    for (int r = 0; r < 4; ++r) {
      dAcc[r] += __shfl_xor(dAcc[r], off);
      nAcc[r] += __shfl_xor(nAcc[r], off);
    }
  }
  if (l15 == 0) {
#pragma unroll
    for (int r = 0; r < 4; ++r) {
      size_t q = (size_t)qbase + w * 16 + quad * 4 + r;
      part[(q * 16 + sc) * 2 + 0] = dAcc[r];
      part[(q * 16 + sc) * 2 + 1] = nAcc[r];
    }
  }
}

__global__ void k_final_r17(const float* __restrict__ part, float* __restrict__ out1) {
  int q = blockIdx.x * 256 + threadIdx.x;
  const float* p = part + (size_t)q * 32;
  float d = 0.f, n = 0.f;
#pragma unroll
  for (int i = 0; i < 16; ++i) { d += p[2 * i]; n += p[2 * i + 1]; }
  out1[q] = n / d;
}

extern "C" void kernel_launch(void* const* d_in, const int* in_sizes, int n_in,
                              void* d_out, int out_size, void* d_ws, size_t ws_size,
                              hipStream_t stream) {
  (void)in_sizes; (void)n_in; (void)out_size; (void)ws_size;
  const float* SF = (const float*)d_in[0];   // fp32
  const int*   SL = (const int*)d_in[1];     // int32
  const float* SV = (const float*)d_in[2];   // fp32
  const float* QF = (const float*)d_in[3];   // fp32

  float* ws = (float*)d_ws;
  float* psum  = ws + OFF_PSUM;
  float* pcnt  = ws + OFF_PCNT;
  float* musum = ws + OFF_MUSUM;
  float* xtx   = ws + OFF_XTX;
  unsigned int* hist = (unsigned int*)(ws + OFF_HIST);
  float* ssum  = ws + OFF_SSUM;
  float* protos= ws + OFF_PROTO;
  float* mu    = ws + OFF_MU;
  float* cov   = ws + OFF_COV;
  float* cptr  = ws + OFF_C;
  float* gptr  = ws + OFF_C + 1;
  float* X1 = ws + OFF_Y;  float* T = ws + OFF_T;  float* X2 = ws + OFF_Y2;
  float* sninv = ws + OFF_SNINV;
  float* qninv = ws + OFF_QNINV;
  float* s2 = ws + OFF_S2; float* q2p = ws + OFF_Q2P;
  float* part = ws + OFF_PART;
  float* G = ws + OFF_G;
  unsigned short* Sh = (unsigned short*)(ws + OFF_SH);
  unsigned short* Gh = (unsigned short*)(ws + OFF_GH);

  float* out0 = (float*)d_out;                   // f32 log_probs [8192 x 64]
  float* out1 = out0 + (size_t)kNQ * kC;         // f32 predictions [8192]

  k_zero_r17<<<(int)((ZERO_FLOATS + 255) / 256), 256, 0, stream>>>(ws);

  // swizzled bf16 copy of support features + row norms
  k_swz_r17<<<kNS / 16, 256, 0, stream>>>(SF, Sh);
  k_norms_r17<<<(kNS + kNQ) / 4, 256, 0, stream>>>(SF, QF, sninv, qninv);

  // classification: LDS segment-sum -> normalize -> GEMM logits + softmax
  k_proto_lds_r17<<<16, 256, 0, stream>>>(SF, SL, sninv, psum, pcnt);
  k_proto_fin_r17<<<kC, 64, 0, stream>>>(psum, pcnt, protos);
  k_logits_r17<<<kNQ / 64, 256, 0, stream>>>(QF, qninv, protos, out0);

  // regression: mean, cov
  k_colsum_r17<<<kNS / 64, 256, 0, stream>>>(SF, musum);
  k_mufin_r17<<<1, 256, 0, stream>>>(musum, mu);
  k_xtx_r17<<<dim3(16, 16), 256, 0, stream>>>(SF, xtx);
  k_cov_r17<<<256, 256, 0, stream>>>(xtx, mu, cov);

  // Newton matrix inverse: X <- X (2I - cov X), X0 = I/c, 6 iterations
  k_cnorm1_r17<<<1, 256, 0, stream>>>(cov, cptr);
  k_newt_init_r17<<<256, 256, 0, stream>>>(cptr, X1);
  float *Xc = X1, *Xn = X2;
  for (int it = 0; it < 6; ++it) {
    k_newt_T_r17<<<256, 256, 0, stream>>>(cov, Xc, T);
    k_newt_X_r17<<<256, 256, 0, stream>>>(Xc, T, Xn);
    float* tmp = Xc; Xc = Xn; Xn = tmp;
  }
  float* M = Xc;   // cov^-1

  // G = (Q - mu) @ M, swizzled bf16 copy, scalar row terms
  k_G_r17<<<dim3(4, kNQ / 64), 256, 0, stream>>>(QF, mu, M, G);
  k_swz_r17<<<kNQ / 16, 256, 0, stream>>>(G, Gh);
  k_q2p_r17<<<kNQ / 4, 256, 0, stream>>>(G, QF, mu, q2p);
  k_s2_r17<<<kNS / 64, 256, 0, stream>>>(SF, mu, M, s2);

  // sampled median -> gamma
  k_median_r17<<<dim3(32, 16), 256, 0, stream>>>(G, SF, q2p, s2, hist, ssum);
  k_gamma_r17<<<1, 256, 0, stream>>>(hist, ssum, gptr);

  // MFMA fused cdist^2 + softmax numer/denom, then finalize
  PrototypicalHead_6210522710389_kernel<<<dim3(128, 16), 256, 0, stream>>>(
      Gh, Sh, q2p, s2, SV, gptr, part);
  k_final_r17<<<kNQ / 256, 256, 0, stream>>>(part, out1);
}